// Round 2
// baseline (181.736 us; speedup 1.0000x reference)
//
#include <hip/hip_runtime.h>

#define TOKENS 65536
#define DIM 64
#define NCODE 1024
#define MARGIN 6e-5f
#define FLAG_CAP 8192
#define TPG 16   // tokens per exact-pass group (r10: 64 -> serialization bound)

#define OUT_IDX_OFF ((size_t)TOKENS * DIM)          // 4194304
#define OUT_LOSS_OFF (OUT_IDX_OFF + TOKENS)         // 4259840

// ws layout (bytes):
#define WS_LOSS   0        // double
#define WS_FLAGC  8        // uint
#define WS_DONEA  12       // uint (global finisher counter)
#define WS_DGRP   16       // uint[512] per-group done counters -> 2064
#define WS_BNORM  2064     // f32[1024] -> 6160
#define WS_CHI    6160     // ushort[65536] -> 137232 (codebook -2c hi, A-frag)
#define WS_CLO    137232   // ushort[65536] -> 268304 (codebook -2c lo)
#define WS_PACKED 268304   // u64[8192] -> 333840 (per-flagged argmin)
#define WS_FLAGS  333840   // int[8192] -> 366608

typedef __attribute__((ext_vector_type(8))) short short8;
typedef __attribute__((ext_vector_type(4))) float f32x4;

// ---------------------------------------------------------------------------
// numpy-bitwise f32 sum-of-squares — VERIFIED absmax=0 (round 2). Do not touch.
// ---------------------------------------------------------------------------
__device__ __forceinline__ float np_sumsq64(const float* __restrict__ x) {
#pragma clang fp contract(off)
    float r[8];
#pragma unroll
    for (int j = 0; j < 8; ++j) r[j] = x[j] * x[j];
#pragma unroll
    for (int i = 8; i < 64; i += 8) {
#pragma unroll
        for (int j = 0; j < 8; ++j) {
            float sq = x[i + j] * x[i + j];
            r[j] = r[j] + sq;
        }
    }
    return ((r[0] + r[1]) + (r[2] + r[3])) + ((r[4] + r[5]) + (r[6] + r[7]));
}

// ---------------------------------------------------------------------------
// Prep: codebook -> bf16 hi/lo A-frags of (-2*C) + bnorm; zero-inits all 516
// control words (loss/flagc/done_all/done_grp[512]). Verified rounds 4-10.
// ---------------------------------------------------------------------------
__global__ __launch_bounds__(256) void vq_prep(
    const float* __restrict__ cb, unsigned short* __restrict__ chi,
    unsigned short* __restrict__ clo, float* __restrict__ bnorm,
    unsigned int* __restrict__ ctrl /* 516 u32 at ws+0 */) {
    int tid = blockIdx.x * 256 + threadIdx.x;   // 0..65535
    if (tid < 516) ctrl[tid] = 0u;
    int j = tid & 7;
    int L = (tid >> 3) & 63;
    int cs = tid >> 9;          // 0..127
    int s = cs & 1, c = cs >> 1;
    int code = c * 16 + (L & 15);
    int d = s * 32 + (L >> 4) * 8 + j;
    float v = -2.0f * cb[(size_t)code * DIM + d];
    unsigned int b = __float_as_uint(v);
    chi[tid] = (unsigned short)(b >> 16);                       // truncation split
    float hf = __uint_as_float(b & 0xFFFF0000u);
    float lo;
    {
#pragma clang fp contract(off)
        lo = v - hf;                                            // exact in f32
    }
    clo[tid] = (unsigned short)(__float_as_uint(lo) >> 16);

    if (tid < NCODE) bnorm[tid] = np_sumsq64(cb + (size_t)tid * DIM);
}

__device__ __forceinline__ void top2_merge(float& a1, float& a2, int& ai,
                                           float b1, float b2, int bi) {
    float n1 = fminf(a1, b1);
    float n2 = fminf(fmaxf(a1, b1), fminf(a2, b2));
    ai = (b1 < a1) ? bi : ai;   // ties keep a (exact ties get flagged anyway)
    a1 = n1; a2 = n2;
}

// ---------------------------------------------------------------------------
// Fast screen, v8 (r12): NO LDS staging, NO main-loop barriers. The 256KB
// codebook frag stream is read by every block -> L2/L3 resident; LDS
// double-buffer (r11: 37.4KB -> 4 blocks/CU cap + 16 block-wide barrier
// drains) was the occupancy limiter, not a needed BW saver. Blocks are now
// 128 threads / 32 tokens, grid 2048 -> 8 blocks/CU = 16 free-running
// waves/CU. Fragments + bnorm prefetched 1 iter ahead into registers.
// Screen arithmetic (MFMA order, min-track, flag rule) bitwise-identical
// to verified v6/v7. Loss partials: 32-token groups on 32-token
// boundaries, same (token,h)->thread map, same 64-lane butterfly, same
// 2048 f64 atomics -> every f32 wave partial bitwise-identical.
// ---------------------------------------------------------------------------
__global__ __launch_bounds__(128, 4) void vq_fast(
    const float* __restrict__ z, const float* __restrict__ cb,
    const unsigned short* __restrict__ cfrag_hi,
    const unsigned short* __restrict__ cfrag_lo,
    const float* __restrict__ bnorm, float* __restrict__ out,
    unsigned int* __restrict__ flag_count, int* __restrict__ flag_list,
    unsigned long long* __restrict__ packed_min,
    double* __restrict__ loss_sum, unsigned int flag_cap) {
    __shared__ int s_best[32];
    __shared__ int s_flag[32];

    const int tid = threadIdx.x;
    const int lane = tid & 63;
    const int w = tid >> 6;                  // 0..1
    const int t0 = blockIdx.x * 32;
    const int tw = t0 + w * 16;              // this wave's 16 tokens
    const int col = lane & 15;
    const int quad = lane >> 4;

    // token B-fragments (bf16 hi/lo), 2 K-steps, in registers
    short8 zhi[2], zlo[2];
#pragma unroll
    for (int s = 0; s < 2; ++s) {
        const float* zp = z + (size_t)(tw + col) * DIM + s * 32 + quad * 8;
        float4 f0 = ((const float4*)zp)[0];
        float4 f1 = ((const float4*)zp)[1];
        float f[8] = {f0.x, f0.y, f0.z, f0.w, f1.x, f1.y, f1.z, f1.w};
        short8 h, l;
#pragma unroll
        for (int j = 0; j < 8; ++j) {
            unsigned int b = __float_as_uint(f[j]);
            h[j] = (short)(b >> 16);
            float hf = __uint_as_float(b & 0xFFFF0000u);
            float lo;
            {
#pragma clang fp contract(off)
                lo = f[j] - hf;
            }
            l[j] = (short)(__float_as_uint(lo) >> 16);
        }
        zhi[s] = h; zlo[s] = l;
    }

    // per-lane fragment pointers; chunk c lives at [c*128 + step*64 + lane]
    const short8* CHp = (const short8*)cfrag_hi + lane;
    const short8* CLp = (const short8*)cfrag_lo + lane;
    const f32x4* bnp = (const f32x4*)bnorm;      // 256 f32x4
    const int koff = quad * 4;

    float m1 = 3.0e38f, m2 = 3.0e38f;
    int bi = 0;

    // prefetch chunk 0
    short8 nh0 = CHp[0], nh1 = CHp[64];
    short8 nl0 = CLp[0], nl1 = CLp[64];
    f32x4 nbn = bnp[quad];

#pragma unroll 2
    for (int c = 0; c < 64; ++c) {
        const short8 ch0 = nh0, ch1 = nh1, cl0 = nl0, cl1 = nl1;
        const f32x4 bn = nbn;
        if (c < 63) {                        // issue next chunk's loads first
            const int b = (c + 1) * 128;
            nh0 = CHp[b]; nh1 = CHp[b + 64];
            nl0 = CLp[b]; nl1 = CLp[b + 64];
            nbn = bnp[(c + 1) * 4 + quad];
        }
        const int cbase = c * 16 + koff;
        f32x4 acc = bn;
        acc = __builtin_amdgcn_mfma_f32_16x16x32_bf16(ch0, zhi[0], acc, 0, 0, 0);
        acc = __builtin_amdgcn_mfma_f32_16x16x32_bf16(cl0, zhi[0], acc, 0, 0, 0);
        acc = __builtin_amdgcn_mfma_f32_16x16x32_bf16(ch0, zlo[0], acc, 0, 0, 0);
        acc = __builtin_amdgcn_mfma_f32_16x16x32_bf16(ch1, zhi[1], acc, 0, 0, 0);
        acc = __builtin_amdgcn_mfma_f32_16x16x32_bf16(cl1, zhi[1], acc, 0, 0, 0);
        acc = __builtin_amdgcn_mfma_f32_16x16x32_bf16(ch1, zlo[1], acc, 0, 0, 0);
#pragma unroll
        for (int i = 0; i < 4; ++i) {
            float u = acc[i];
            float om1 = m1;
            bool lt = u < om1;
            float fm = fminf(m2, u);
            m2 = lt ? om1 : fm;
            m1 = lt ? u : om1;
            bi = lt ? (cbase + i) : bi;
        }
    }

    // in-wave quad merge (lanes l, l^16, l^32, l^48 share a token column)
    {
        float a1 = m1, a2 = m2;
        int ai = bi;
        {
            float o1 = __shfl_xor(a1, 16); float o2 = __shfl_xor(a2, 16);
            int oi = __shfl_xor(ai, 16);
            top2_merge(a1, a2, ai, o1, o2, oi);
        }
        {
            float o1 = __shfl_xor(a1, 32); float o2 = __shfl_xor(a2, 32);
            int oi = __shfl_xor(ai, 32);
            top2_merge(a1, a2, ai, o1, o2, oi);
        }
        if (quad == 0) {
            const int slot = w * 16 + col;
            int fl = (a2 - a1) < MARGIN;
            if (fl) {
                unsigned int pos = atomicAdd(flag_count, 1u);
                if (pos >= flag_cap) fl = 0;
                else {
                    flag_list[pos] = t0 + slot;
                    packed_min[pos] = ~0ull;   // lazy init (no memset node)
                }
            }
            s_best[slot] = ai;
            s_flag[slot] = fl;
        }
    }
    __syncthreads();

    // epilogue: wave 0 covers tokens 0..31 with the r6-verified per-thread
    // 32-float partial and the same 64-lane butterfly; wave 1 idle (exact 0).
    const int et = tid >> 1, h = tid & 1;
    float loss_t = 0.0f;
    if (et < 32 && !s_flag[et]) {
        const int B = s_best[et];
        const float4* cq  = (const float4*)(cb + (size_t)B * DIM + h * 32);
        const float4* zq4 = (const float4*)(z + (size_t)(t0 + et) * DIM + h * 32);
        float4* o4 = (float4*)(out + (size_t)(t0 + et) * DIM + h * 32);
#pragma unroll
        for (int jj = 0; jj < 8; ++jj) {
#pragma clang fp contract(off)
            float4 cc = cq[jj];
            float4 zz = zq4[jj];
            float d0 = cc.x - zz.x, d1 = cc.y - zz.y;
            float d2 = cc.z - zz.z, d3 = cc.w - zz.w;
            float4 o;
            o.x = zz.x + d0; o.y = zz.y + d1;
            o.z = zz.z + d2; o.w = zz.w + d3;
            o4[jj] = o;
            loss_t = __fmaf_rn(d0, d0, loss_t);
            loss_t = __fmaf_rn(d1, d1, loss_t);
            loss_t = __fmaf_rn(d2, d2, loss_t);
            loss_t = __fmaf_rn(d3, d3, loss_t);
        }
        if (h == 0) out[OUT_IDX_OFF + t0 + et] = (float)B;
    }
#pragma unroll
    for (int off = 32; off > 0; off >>= 1)
        loss_t += __shfl_down(loss_t, off);
    if (lane == 0 && w == 0) atomicAdd(loss_sum, (double)loss_t);
}

__device__ __forceinline__ unsigned long long shfl_down_u64(unsigned long long v, int off) {
    unsigned int lo = (unsigned int)v, hi = (unsigned int)(v >> 32);
    lo = __shfl_down(lo, off);
    hi = __shfl_down(hi, off);
    return ((unsigned long long)hi << 32) | lo;
}

// ---------------------------------------------------------------------------
// Exact numpy-bitwise pass, v4: 16 tokens/group (r10's 64 was serialization-
// bound at ~60 active blocks). Grid 2048 quarter-blocks; ~4x parallelism,
// serial chain /4. Fused finish per group (4th quarter writes outputs; last
// group writes loss). Bitwise arithmetic identical to verified rounds 6-10.
// ---------------------------------------------------------------------------
__global__ __launch_bounds__(256) void vq_exact_min(
    const float* __restrict__ z, const float* __restrict__ cb,
    const float* __restrict__ bnorm,
    const unsigned int* __restrict__ flag_count,
    const int* __restrict__ flag_list,
    unsigned long long* __restrict__ packed_min,
    unsigned int* __restrict__ done_grp, unsigned int* __restrict__ done_all,
    float* __restrict__ out, double* __restrict__ loss_sum,
    unsigned int flag_cap) {
    __shared__ float zsh[TPG * 68];
    __shared__ float szs[TPG];
    __shared__ unsigned int s_old;

    const int tid = threadIdx.x;
    const int w = tid >> 6;
    const int lane = tid & 63;
    unsigned int count = *flag_count;
    if (count > flag_cap) count = flag_cap;
    const unsigned int ngroups = (count + TPG - 1) / TPG;   // <= 512

    if (count == 0) {   // no flagged tokens: block 0 writes the loss
        if (blockIdx.x == 0 && tid == 0) {
            double L = atomicAdd(loss_sum, 0.0);
            out[OUT_LOSS_OFF] = (float)(2.0 * L / (double)((size_t)TOKENS * DIM));
        }
        return;
    }

    const int q = blockIdx.x & 3;
    const unsigned int g = blockIdx.x >> 2;          // 0..511
    if (g >= ngroups) return;

    const int k = q * 256 + w * 64 + lane;           // this lane's code

    float row[DIM];
    {
        const float4* c4 = (const float4*)(cb + (size_t)k * DIM);
#pragma unroll
        for (int j = 0; j < 16; ++j) {
            float4 v = c4[j];
            row[4 * j + 0] = v.x; row[4 * j + 1] = v.y;
            row[4 * j + 2] = v.z; row[4 * j + 3] = v.w;
        }
    }
    const float bnk = bnorm[k];

    {
        const int i = tid >> 2, part = tid & 3;
        if (i < TPG) {
            const unsigned int li = g * TPG + i;
            if (li < count) {
                const int t = flag_list[li];
                const float4* zp = (const float4*)(z + (size_t)t * DIM + part * 16);
                float4* dst = (float4*)(zsh + i * 68 + part * 16);
#pragma unroll
                for (int e = 0; e < 4; ++e) dst[e] = zp[e];
            }
        }
    }
    __syncthreads();
    if (tid < TPG) szs[tid] = np_sumsq64(zsh + tid * 68);
    __syncthreads();

    for (int tt = 0; tt < TPG; ++tt) {
        const unsigned int li = g * TPG + tt;
        const float* zp = zsh + tt * 68;             // wave-uniform -> broadcast
        float l16[16];
#pragma unroll
        for (int g2 = 0; g2 < 4; ++g2) {
            float4 v0 = ((const float4*)(zp + 4 * g2))[0];
            float4 v1 = ((const float4*)(zp + 16 + 4 * g2))[0];
            float4 v2 = ((const float4*)(zp + 32 + 4 * g2))[0];
            float4 v3 = ((const float4*)(zp + 48 + 4 * g2))[0];
            float a0[4] = {v0.x, v0.y, v0.z, v0.w};
            float a1[4] = {v1.x, v1.y, v1.z, v1.w};
            float a2[4] = {v2.x, v2.y, v2.z, v2.w};
            float a3[4] = {v3.x, v3.y, v3.z, v3.w};
#pragma unroll
            for (int e = 0; e < 4; ++e) {
#pragma clang fp contract(off)
                int jj = 4 * g2 + e;
                float acc = a3[e] * row[48 + jj];
                acc = __fmaf_rn(a2[e], row[32 + jj], acc);
                acc = __fmaf_rn(a1[e], row[16 + jj], acc);
                acc = __fmaf_rn(a0[e], row[jj],      acc);
                l16[jj] = acc;
            }
        }
        float e_np;
        {
#pragma clang fp contract(off)
#pragma unroll
            for (int jj = 0; jj < 8; ++jj) l16[jj] = l16[jj] + l16[jj + 8];
#pragma unroll
            for (int jj = 0; jj < 4; ++jj) l16[jj] = l16[jj] + l16[jj + 4];
            l16[0] = l16[0] + l16[2];
            l16[1] = l16[1] + l16[3];
            e_np = l16[0] + l16[1];
        }
        float dd;
        {
#pragma clang fp contract(off)
            float t1 = szs[tt] + bnk;
            float mm = 2.0f * e_np;
            dd = t1 - mm;
        }
        unsigned long long pk =
            ((unsigned long long)__float_as_uint(dd) << 10) | (unsigned int)k;
#pragma unroll
        for (int off = 32; off > 0; off >>= 1) {
            unsigned long long o = shfl_down_u64(pk, off);
            pk = (o < pk) ? o : pk;
        }
        if (lane == 0 && li < count)
            atomicMin(&packed_min[li], pk);
    }

    // ---- fused finish: 4th quarter-block of this group writes outputs ----
    __threadfence();
    __syncthreads();
    if (tid == 0) s_old = atomicAdd(&done_grp[g], 1u);
    __syncthreads();
    if (s_old != 3u) return;
    __threadfence();

    for (int tt = w * (TPG / 4); tt < (w + 1) * (TPG / 4); ++tt) {
        const unsigned int li = g * TPG + tt;
        if (li >= count) break;
        const int t = flag_list[li];
        const unsigned long long pk = atomicAdd(&packed_min[li], 0ull);  // coherent
        const int best = (int)(pk & 1023ull);
        const float zl = zsh[tt * 68 + lane];
        const float zq = cb[(size_t)best * DIM + lane];
        float d, o;
        {
#pragma clang fp contract(off)
            d = zq - zl;
            o = zl + d;
        }
        out[(size_t)t * DIM + lane] = o;
        float l2 = d * d;
#pragma unroll
        for (int off = 32; off > 0; off >>= 1)
            l2 += __shfl_down(l2, off);
        if (lane == 0) {
            out[OUT_IDX_OFF + t] = (float)best;
            atomicAdd(loss_sum, (double)l2);
        }
    }

    __threadfence();
    __syncthreads();
    if (tid == 0) {
        unsigned int old = atomicAdd(done_all, 1u);
        if (old == ngroups - 1) {
            double L = atomicAdd(loss_sum, 0.0);   // coherent read-through
            out[OUT_LOSS_OFF] = (float)(2.0 * L / (double)((size_t)TOKENS * DIM));
        }
    }
}

extern "C" void kernel_launch(void* const* d_in, const int* in_sizes, int n_in,
                              void* d_out, int out_size, void* d_ws, size_t ws_size,
                              hipStream_t stream) {
    const float* z  = (const float*)d_in[0];   // [8,8192,64] f32
    const float* cb = (const float*)d_in[1];   // [1024,64] f32
    float* out = (float*)d_out;

    char* ws = (char*)d_ws;
    double* loss_sum = (double*)(ws + WS_LOSS);
    unsigned int* flag_count = (unsigned int*)(ws + WS_FLAGC);
    unsigned int* done_all = (unsigned int*)(ws + WS_DONEA);
    unsigned int* done_grp = (unsigned int*)(ws + WS_DGRP);
    float* bnorm = (float*)(ws + WS_BNORM);
    unsigned short* chi = (unsigned short*)(ws + WS_CHI);
    unsigned short* clo = (unsigned short*)(ws + WS_CLO);
    unsigned long long* packed = (unsigned long long*)(ws + WS_PACKED);
    int* flag_list = (int*)(ws + WS_FLAGS);

    unsigned int cap = 0;
    if (ws_size > WS_FLAGS + 4) {
        size_t c = (ws_size - WS_FLAGS) / 4;
        cap = (c > FLAG_CAP) ? FLAG_CAP : (unsigned int)c;
    }

    vq_prep<<<dim3(256), dim3(256), 0, stream>>>(
        cb, chi, clo, bnorm, (unsigned int*)ws);
    vq_fast<<<dim3(TOKENS / 32), dim3(128), 0, stream>>>(
        z, cb, chi, clo, bnorm, out, flag_count, flag_list, packed, loss_sum, cap);
    vq_exact_min<<<dim3(2048), dim3(256), 0, stream>>>(
        z, cb, bnorm, flag_count, flag_list, packed, done_grp, done_all,
        out, loss_sum, cap);
}

// Round 3
// 142.696 us; speedup vs baseline: 1.2736x; 1.2736x over previous
//
#include <hip/hip_runtime.h>

#define TOKENS 65536
#define DIM 64
#define NCODE 1024
// fp16-screen margin (unscaled). Screen error bound: ~192 f32 roundings x
// ulp(3e5 scaled)/2^21 ~ 2.9e-6 worst-case; 1e-5 gives 3.4x headroom.
#define MARGIN 1e-5f
#define MARGINS (MARGIN * 2097152.0f)   // scaled-domain threshold (x 2^21)
#define FLAG_CAP 8192
#define TPG 16   // tokens per exact-pass group

#define OUT_IDX_OFF ((size_t)TOKENS * DIM)          // 4194304
#define OUT_LOSS_OFF (OUT_IDX_OFF + TOKENS)         // 4259840

// ws layout (bytes):
#define WS_LOSS   0        // double
#define WS_FLAGC  8        // uint
#define WS_DONEA  12       // uint (global finisher counter)
#define WS_DGRP   16       // uint[512] per-group done counters -> 2064
#define WS_BNORM  2064     // f32[1024] -> 6160 (unscaled, exact pass)
#define WS_BNS    6160     // f32[1024] -> 10256 (x2^21, screen)
#define WS_CHI    10256    // ushort[65536] -> 141328 (fp16 hi of -8192*c)
#define WS_CLO    141328   // ushort[65536] -> 272400 (fp16 lo)
#define WS_PACKED 272400   // u64[8192] -> 337936 (per-flagged argmin)
#define WS_FLAGS  337936   // int[8192] -> 370704

typedef __attribute__((ext_vector_type(8))) short short8;
typedef __attribute__((ext_vector_type(8))) _Float16 half8;
typedef __attribute__((ext_vector_type(4))) float f32x4;

static __device__ __forceinline__ half8 as_h8(short8 v) {
    return __builtin_bit_cast(half8, v);
}

// ---------------------------------------------------------------------------
// numpy-bitwise f32 sum-of-squares — VERIFIED absmax=0 (round 2). Do not touch.
// ---------------------------------------------------------------------------
__device__ __forceinline__ float np_sumsq64(const float* __restrict__ x) {
#pragma clang fp contract(off)
    float r[8];
#pragma unroll
    for (int j = 0; j < 8; ++j) r[j] = x[j] * x[j];
#pragma unroll
    for (int i = 8; i < 64; i += 8) {
#pragma unroll
        for (int j = 0; j < 8; ++j) {
            float sq = x[i + j] * x[i + j];
            r[j] = r[j] + sq;
        }
    }
    return ((r[0] + r[1]) + (r[2] + r[3])) + ((r[4] + r[5]) + (r[6] + r[7]));
}

// ---------------------------------------------------------------------------
// Prep v2 (r13): codebook -> fp16 hi/lo A-frags of (-2*4096*C) + bnorm
// (unscaled, exact pass) + bns (= bnorm * 2^21, screen). Scales are exact
// powers of two -> argmin and top-2 gap invariant. Zero-inits all 516
// control words. Frag layout identical to verified rounds.
// ---------------------------------------------------------------------------
__global__ __launch_bounds__(256) void vq_prep(
    const float* __restrict__ cb, unsigned short* __restrict__ chi,
    unsigned short* __restrict__ clo, float* __restrict__ bnorm,
    float* __restrict__ bns,
    unsigned int* __restrict__ ctrl /* 516 u32 at ws+0 */) {
    int tid = blockIdx.x * 256 + threadIdx.x;   // 0..65535
    if (tid < 516) ctrl[tid] = 0u;
    int j = tid & 7;
    int L = (tid >> 3) & 63;
    int cs = tid >> 9;          // 0..127
    int s = cs & 1, c = cs >> 1;
    int code = c * 16 + (L & 15);
    int d = s * 32 + (L >> 4) * 8 + j;
    float v = -8192.0f * cb[(size_t)code * DIM + d];   // -2c * 4096 (exact)
    _Float16 h = (_Float16)v;                          // RN f32->f16
    float hf = (float)h;
    float lo;
    {
#pragma clang fp contract(off)
        lo = v - hf;                                   // exact in f32
    }
    _Float16 l = (_Float16)lo;
    chi[tid] = __builtin_bit_cast(unsigned short, h);
    clo[tid] = __builtin_bit_cast(unsigned short, l);

    if (tid < NCODE) {
        float bn = np_sumsq64(cb + (size_t)tid * DIM);
        bnorm[tid] = bn;
        bns[tid] = bn * 2097152.0f;                    // x 2^21 (exact)
    }
}

__device__ __forceinline__ void top2_merge(float& a1, float& a2, int& ai,
                                           float b1, float b2, int bi) {
    float n1 = fminf(a1, b1);
    float n2 = fminf(fmaxf(a1, b1), fminf(a2, b2));
    ai = (b1 < a1) ? bi : ai;   // ties keep a (exact ties get flagged anyway)
    a1 = n1; a2 = n2;
}

// ---------------------------------------------------------------------------
// Fast screen, v9 (r13): structural revert to the verified r11/v7 LDS
// double-buffer shape (57.6us, best) — r12's no-LDS variant regressed
// (per-wave L2 streams, MfmaUtil 16.5->12.5). Change this round: fp16
// hi/lo fragments with exact pow2 scaling (z*512, -2c*4096) -> product
// accuracy 2^-22 vs bf16's 2^-16 -> MARGIN 6e-5 -> 1e-5 -> ~6x fewer
// flagged tokens feeding the exact pass. MFMA count/shape unchanged
// (f16 rate = bf16 rate). Flag rule, min-track, epilogue structure
// identical to verified rounds (loss partials bitwise-identical).
// ---------------------------------------------------------------------------
__global__ __launch_bounds__(256, 4) void vq_fast(
    const float* __restrict__ z, const float* __restrict__ cb,
    const unsigned short* __restrict__ cfrag_hi,
    const unsigned short* __restrict__ cfrag_lo,
    const float* __restrict__ bnorm_s, float* __restrict__ out,
    unsigned int* __restrict__ flag_count, int* __restrict__ flag_list,
    unsigned long long* __restrict__ packed_min,
    double* __restrict__ loss_sum, unsigned int flag_cap) {
    __shared__ short8 sh_hi[2][512];   // [buf][(cc*2+step)*64 + lane], 8KB each
    __shared__ short8 sh_lo[2][512];
    __shared__ float bn_lds[NCODE];
    __shared__ int s_best[64];
    __shared__ int s_flag[64];

    const int tid = threadIdx.x;
    const int lane = tid & 63;
    const int w = tid >> 6;
    const int t0 = blockIdx.x * 64;
    const int tw = t0 + w * 16;              // this wave's 16 tokens
    const int col = lane & 15;
    const int quad = lane >> 4;

    // stage scaled bnorm into LDS (4 KB)
    ((float4*)bn_lds)[tid] = ((const float4*)bnorm_s)[tid];

    // token B-fragments (fp16 hi/lo of z*512), 2 K-steps, in registers
    half8 zhi[2], zlo[2];
#pragma unroll
    for (int s = 0; s < 2; ++s) {
        const float* zp = z + (size_t)(tw + col) * DIM + s * 32 + quad * 8;
        float4 f0 = ((const float4*)zp)[0];
        float4 f1 = ((const float4*)zp)[1];
        float f[8] = {f0.x, f0.y, f0.z, f0.w, f1.x, f1.y, f1.z, f1.w};
        half8 h, l;
#pragma unroll
        for (int j = 0; j < 8; ++j) {
            float sv = f[j] * 512.0f;        // exact pow2 scale
            _Float16 hh = (_Float16)sv;      // RN
            float hf = (float)hh;
            float lo;
            {
#pragma clang fp contract(off)
                lo = sv - hf;                // exact in f32
            }
            h[j] = hh;
            l[j] = (_Float16)lo;
        }
        zhi[s] = h; zlo[s] = l;
    }

    const short8* CH = (const short8*)cfrag_hi;   // 4096 short8 (64 chunks)
    const short8* CL = (const short8*)cfrag_lo;

    // stage group 0 (4 chunks = 512 short8 per array; 2 per thread per array)
    {
        short8 a0 = CH[tid], a1 = CH[tid + 256];
        short8 b0 = CL[tid], b1 = CL[tid + 256];
        sh_hi[0][tid] = a0; sh_hi[0][tid + 256] = a1;
        sh_lo[0][tid] = b0; sh_lo[0][tid + 256] = b1;
    }
    __syncthreads();

    float m1 = 3.0e38f, m2 = 3.0e38f;
    int bi = 0;
    const int koff = quad * 4;

    for (int g = 0; g < 16; ++g) {
        const int buf = g & 1;
        short8 a0, a1, b0, b1;
        if (g < 15) {               // issue next group's loads first
            const int base = (g + 1) * 512 + tid;
            a0 = CH[base]; a1 = CH[base + 256];
            b0 = CL[base]; b1 = CL[base + 256];
        }
#pragma unroll
        for (int cc = 0; cc < 4; ++cc) {
            const int c = g * 4 + cc;
            short8 ch0 = sh_hi[buf][(cc * 2 + 0) * 64 + lane];
            short8 ch1 = sh_hi[buf][(cc * 2 + 1) * 64 + lane];
            short8 cl0 = sh_lo[buf][(cc * 2 + 0) * 64 + lane];
            short8 cl1 = sh_lo[buf][(cc * 2 + 1) * 64 + lane];
            const int cbase = c * 16 + koff;
            const f32x4 bn = *(const f32x4*)&bn_lds[cbase];
            f32x4 acc = bn;
            acc = __builtin_amdgcn_mfma_f32_16x16x32_f16(as_h8(ch0), zhi[0], acc, 0, 0, 0);
            acc = __builtin_amdgcn_mfma_f32_16x16x32_f16(as_h8(cl0), zhi[0], acc, 0, 0, 0);
            acc = __builtin_amdgcn_mfma_f32_16x16x32_f16(as_h8(ch0), zlo[0], acc, 0, 0, 0);
            acc = __builtin_amdgcn_mfma_f32_16x16x32_f16(as_h8(ch1), zhi[1], acc, 0, 0, 0);
            acc = __builtin_amdgcn_mfma_f32_16x16x32_f16(as_h8(cl1), zhi[1], acc, 0, 0, 0);
            acc = __builtin_amdgcn_mfma_f32_16x16x32_f16(as_h8(ch1), zlo[1], acc, 0, 0, 0);
#pragma unroll
            for (int i = 0; i < 4; ++i) {
                float u = acc[i];
                float om1 = m1;
                bool lt = u < om1;
                float fm = fminf(m2, u);
                m2 = lt ? om1 : fm;
                m1 = lt ? u : om1;
                bi = lt ? (cbase + i) : bi;
            }
        }
        if (g < 15) {
            sh_hi[buf ^ 1][tid] = a0; sh_hi[buf ^ 1][tid + 256] = a1;
            sh_lo[buf ^ 1][tid] = b0; sh_lo[buf ^ 1][tid + 256] = b1;
            __syncthreads();
        }
    }

    // in-wave quad merge (lanes l, l^16, l^32, l^48 share a token column)
    {
        float a1 = m1, a2 = m2;
        int ai = bi;
        {
            float o1 = __shfl_xor(a1, 16); float o2 = __shfl_xor(a2, 16);
            int oi = __shfl_xor(ai, 16);
            top2_merge(a1, a2, ai, o1, o2, oi);
        }
        {
            float o1 = __shfl_xor(a1, 32); float o2 = __shfl_xor(a2, 32);
            int oi = __shfl_xor(ai, 32);
            top2_merge(a1, a2, ai, o1, o2, oi);
        }
        if (quad == 0) {
            const int slot = w * 16 + col;
            int fl = (a2 - a1) < MARGINS;
            if (fl) {
                unsigned int pos = atomicAdd(flag_count, 1u);
                if (pos >= flag_cap) fl = 0;
                else {
                    flag_list[pos] = t0 + slot;
                    packed_min[pos] = ~0ull;   // lazy init (no memset node)
                }
            }
            s_best[slot] = ai;
            s_flag[slot] = fl;
        }
    }
    __syncthreads();

    // epilogue: 2 threads per token, 32 floats each (r6-verified partial
    // structure); flagged deferred.
    const int et = tid >> 1, h = tid & 1;
    float loss_t = 0.0f;
    if (et < 64 && !s_flag[et]) {
        const int B = s_best[et];
        const float4* cq  = (const float4*)(cb + (size_t)B * DIM + h * 32);
        const float4* zq4 = (const float4*)(z + (size_t)(t0 + et) * DIM + h * 32);
        float4* o4 = (float4*)(out + (size_t)(t0 + et) * DIM + h * 32);
#pragma unroll
        for (int jj = 0; jj < 8; ++jj) {
#pragma clang fp contract(off)
            float4 cc = cq[jj];
            float4 zz = zq4[jj];
            float d0 = cc.x - zz.x, d1 = cc.y - zz.y;
            float d2 = cc.z - zz.z, d3 = cc.w - zz.w;
            float4 o;
            o.x = zz.x + d0; o.y = zz.y + d1;
            o.z = zz.z + d2; o.w = zz.w + d3;
            o4[jj] = o;
            loss_t = __fmaf_rn(d0, d0, loss_t);
            loss_t = __fmaf_rn(d1, d1, loss_t);
            loss_t = __fmaf_rn(d2, d2, loss_t);
            loss_t = __fmaf_rn(d3, d3, loss_t);
        }
        if (h == 0) out[OUT_IDX_OFF + t0 + et] = (float)B;
    }
#pragma unroll
    for (int off = 32; off > 0; off >>= 1)
        loss_t += __shfl_down(loss_t, off);
    if (lane == 0 && w < 2) atomicAdd(loss_sum, (double)loss_t);
}

__device__ __forceinline__ unsigned long long shfl_down_u64(unsigned long long v, int off) {
    unsigned int lo = (unsigned int)v, hi = (unsigned int)(v >> 32);
    lo = __shfl_down(lo, off);
    hi = __shfl_down(hi, off);
    return ((unsigned long long)hi << 32) | lo;
}

// ---------------------------------------------------------------------------
// Exact numpy-bitwise pass, v4: UNCHANGED (verified rounds 6-10). Uses
// unscaled bnorm; arithmetic bitwise-identical.
// ---------------------------------------------------------------------------
__global__ __launch_bounds__(256) void vq_exact_min(
    const float* __restrict__ z, const float* __restrict__ cb,
    const float* __restrict__ bnorm,
    const unsigned int* __restrict__ flag_count,
    const int* __restrict__ flag_list,
    unsigned long long* __restrict__ packed_min,
    unsigned int* __restrict__ done_grp, unsigned int* __restrict__ done_all,
    float* __restrict__ out, double* __restrict__ loss_sum,
    unsigned int flag_cap) {
    __shared__ float zsh[TPG * 68];
    __shared__ float szs[TPG];
    __shared__ unsigned int s_old;

    const int tid = threadIdx.x;
    const int w = tid >> 6;
    const int lane = tid & 63;
    unsigned int count = *flag_count;
    if (count > flag_cap) count = flag_cap;
    const unsigned int ngroups = (count + TPG - 1) / TPG;   // <= 512

    if (count == 0) {   // no flagged tokens: block 0 writes the loss
        if (blockIdx.x == 0 && tid == 0) {
            double L = atomicAdd(loss_sum, 0.0);
            out[OUT_LOSS_OFF] = (float)(2.0 * L / (double)((size_t)TOKENS * DIM));
        }
        return;
    }

    const int q = blockIdx.x & 3;
    const unsigned int g = blockIdx.x >> 2;          // 0..511
    if (g >= ngroups) return;

    const int k = q * 256 + w * 64 + lane;           // this lane's code

    float row[DIM];
    {
        const float4* c4 = (const float4*)(cb + (size_t)k * DIM);
#pragma unroll
        for (int j = 0; j < 16; ++j) {
            float4 v = c4[j];
            row[4 * j + 0] = v.x; row[4 * j + 1] = v.y;
            row[4 * j + 2] = v.z; row[4 * j + 3] = v.w;
        }
    }
    const float bnk = bnorm[k];

    {
        const int i = tid >> 2, part = tid & 3;
        if (i < TPG) {
            const unsigned int li = g * TPG + i;
            if (li < count) {
                const int t = flag_list[li];
                const float4* zp = (const float4*)(z + (size_t)t * DIM + part * 16);
                float4* dst = (float4*)(zsh + i * 68 + part * 16);
#pragma unroll
                for (int e = 0; e < 4; ++e) dst[e] = zp[e];
            }
        }
    }
    __syncthreads();
    if (tid < TPG) szs[tid] = np_sumsq64(zsh + tid * 68);
    __syncthreads();

    for (int tt = 0; tt < TPG; ++tt) {
        const unsigned int li = g * TPG + tt;
        const float* zp = zsh + tt * 68;             // wave-uniform -> broadcast
        float l16[16];
#pragma unroll
        for (int g2 = 0; g2 < 4; ++g2) {
            float4 v0 = ((const float4*)(zp + 4 * g2))[0];
            float4 v1 = ((const float4*)(zp + 16 + 4 * g2))[0];
            float4 v2 = ((const float4*)(zp + 32 + 4 * g2))[0];
            float4 v3 = ((const float4*)(zp + 48 + 4 * g2))[0];
            float a0[4] = {v0.x, v0.y, v0.z, v0.w};
            float a1[4] = {v1.x, v1.y, v1.z, v1.w};
            float a2[4] = {v2.x, v2.y, v2.z, v2.w};
            float a3[4] = {v3.x, v3.y, v3.z, v3.w};
#pragma unroll
            for (int e = 0; e < 4; ++e) {
#pragma clang fp contract(off)
                int jj = 4 * g2 + e;
                float acc = a3[e] * row[48 + jj];
                acc = __fmaf_rn(a2[e], row[32 + jj], acc);
                acc = __fmaf_rn(a1[e], row[16 + jj], acc);
                acc = __fmaf_rn(a0[e], row[jj],      acc);
                l16[jj] = acc;
            }
        }
        float e_np;
        {
#pragma clang fp contract(off)
#pragma unroll
            for (int jj = 0; jj < 8; ++jj) l16[jj] = l16[jj] + l16[jj + 8];
#pragma unroll
            for (int jj = 0; jj < 4; ++jj) l16[jj] = l16[jj] + l16[jj + 4];
            l16[0] = l16[0] + l16[2];
            l16[1] = l16[1] + l16[3];
            e_np = l16[0] + l16[1];
        }
        float dd;
        {
#pragma clang fp contract(off)
            float t1 = szs[tt] + bnk;
            float mm = 2.0f * e_np;
            dd = t1 - mm;
        }
        unsigned long long pk =
            ((unsigned long long)__float_as_uint(dd) << 10) | (unsigned int)k;
#pragma unroll
        for (int off = 32; off > 0; off >>= 1) {
            unsigned long long o = shfl_down_u64(pk, off);
            pk = (o < pk) ? o : pk;
        }
        if (lane == 0 && li < count)
            atomicMin(&packed_min[li], pk);
    }

    // ---- fused finish: 4th quarter-block of this group writes outputs ----
    __threadfence();
    __syncthreads();
    if (tid == 0) s_old = atomicAdd(&done_grp[g], 1u);
    __syncthreads();
    if (s_old != 3u) return;
    __threadfence();

    for (int tt = w * (TPG / 4); tt < (w + 1) * (TPG / 4); ++tt) {
        const unsigned int li = g * TPG + tt;
        if (li >= count) break;
        const int t = flag_list[li];
        const unsigned long long pk = atomicAdd(&packed_min[li], 0ull);  // coherent
        const int best = (int)(pk & 1023ull);
        const float zl = zsh[tt * 68 + lane];
        const float zq = cb[(size_t)best * DIM + lane];
        float d, o;
        {
#pragma clang fp contract(off)
            d = zq - zl;
            o = zl + d;
        }
        out[(size_t)t * DIM + lane] = o;
        float l2 = d * d;
#pragma unroll
        for (int off = 32; off > 0; off >>= 1)
            l2 += __shfl_down(l2, off);
        if (lane == 0) {
            out[OUT_IDX_OFF + t] = (float)best;
            atomicAdd(loss_sum, (double)l2);
        }
    }

    __threadfence();
    __syncthreads();
    if (tid == 0) {
        unsigned int old = atomicAdd(done_all, 1u);
        if (old == ngroups - 1) {
            double L = atomicAdd(loss_sum, 0.0);   // coherent read-through
            out[OUT_LOSS_OFF] = (float)(2.0 * L / (double)((size_t)TOKENS * DIM));
        }
    }
}

extern "C" void kernel_launch(void* const* d_in, const int* in_sizes, int n_in,
                              void* d_out, int out_size, void* d_ws, size_t ws_size,
                              hipStream_t stream) {
    const float* z  = (const float*)d_in[0];   // [8,8192,64] f32
    const float* cb = (const float*)d_in[1];   // [1024,64] f32
    float* out = (float*)d_out;

    char* ws = (char*)d_ws;
    double* loss_sum = (double*)(ws + WS_LOSS);
    unsigned int* flag_count = (unsigned int*)(ws + WS_FLAGC);
    unsigned int* done_all = (unsigned int*)(ws + WS_DONEA);
    unsigned int* done_grp = (unsigned int*)(ws + WS_DGRP);
    float* bnorm = (float*)(ws + WS_BNORM);
    float* bns = (float*)(ws + WS_BNS);
    unsigned short* chi = (unsigned short*)(ws + WS_CHI);
    unsigned short* clo = (unsigned short*)(ws + WS_CLO);
    unsigned long long* packed = (unsigned long long*)(ws + WS_PACKED);
    int* flag_list = (int*)(ws + WS_FLAGS);

    unsigned int cap = 0;
    if (ws_size > WS_FLAGS + 4) {
        size_t c = (ws_size - WS_FLAGS) / 4;
        cap = (c > FLAG_CAP) ? FLAG_CAP : (unsigned int)c;
    }

    vq_prep<<<dim3(256), dim3(256), 0, stream>>>(
        cb, chi, clo, bnorm, bns, (unsigned int*)ws);
    vq_fast<<<dim3(TOKENS / 64), dim3(256), 0, stream>>>(
        z, cb, chi, clo, bns, out, flag_count, flag_list, packed, loss_sum, cap);
    vq_exact_min<<<dim3(2048), dim3(256), 0, stream>>>(
        z, cb, bnorm, flag_count, flag_list, packed, done_grp, done_all,
        out, loss_sum, cap);
}

// Round 4
// 142.281 us; speedup vs baseline: 1.2773x; 1.0029x over previous
//
#include <hip/hip_runtime.h>

#define TOKENS 65536
#define DIM 64
#define NCODE 1024
// fp16-screen margin (unscaled). Screen error bound: ~192 f32 roundings x
// ulp(3e5 scaled)/2^21 ~ 2.9e-6 worst-case; 1e-5 gives 3.4x headroom.
#define MARGIN 1e-5f
#define MARGINS (MARGIN * 2097152.0f)   // scaled-domain threshold (x 2^21)
#define FLAG_CAP 8192
#define TPG 16   // tokens per exact-pass group

#define OUT_IDX_OFF ((size_t)TOKENS * DIM)          // 4194304
#define OUT_LOSS_OFF (OUT_IDX_OFF + TOKENS)         // 4259840

// ws layout (bytes):
#define WS_LOSS   0        // double
#define WS_FLAGC  8        // uint
#define WS_DONEA  12       // uint (global finisher counter)
#define WS_DGRP   16       // uint[512] per-group done counters -> 2064
#define WS_BNORM  2064     // f32[1024] -> 6160 (unscaled, exact pass)
#define WS_BNS    6160     // f32[1024] -> 10256 (x2^21, screen)
#define WS_CHI    10256    // ushort[65536] -> 141328 (fp16 hi of -8192*c)
#define WS_CLO    141328   // ushort[65536] -> 272400 (fp16 lo)
#define WS_PACKED 272400   // u64[8192] -> 337936 (per-flagged argmin)
#define WS_FLAGS  337936   // int[8192] -> 370704

typedef __attribute__((ext_vector_type(8))) short short8;
typedef __attribute__((ext_vector_type(8))) _Float16 half8;
typedef __attribute__((ext_vector_type(4))) float f32x4;

static __device__ __forceinline__ half8 as_h8(short8 v) {
    return __builtin_bit_cast(half8, v);
}

// ---------------------------------------------------------------------------
// numpy-bitwise f32 sum-of-squares — VERIFIED absmax=0 (round 2). Do not touch.
// ---------------------------------------------------------------------------
__device__ __forceinline__ float np_sumsq64(const float* __restrict__ x) {
#pragma clang fp contract(off)
    float r[8];
#pragma unroll
    for (int j = 0; j < 8; ++j) r[j] = x[j] * x[j];
#pragma unroll
    for (int i = 8; i < 64; i += 8) {
#pragma unroll
        for (int j = 0; j < 8; ++j) {
            float sq = x[i + j] * x[i + j];
            r[j] = r[j] + sq;
        }
    }
    return ((r[0] + r[1]) + (r[2] + r[3])) + ((r[4] + r[5]) + (r[6] + r[7]));
}

// ---------------------------------------------------------------------------
// Prep v2 (r13, UNCHANGED): codebook -> fp16 hi/lo A-frags of (-2*4096*C)
// + bnorm (unscaled, exact pass) + bns (= bnorm * 2^21, screen).
// ---------------------------------------------------------------------------
__global__ __launch_bounds__(256) void vq_prep(
    const float* __restrict__ cb, unsigned short* __restrict__ chi,
    unsigned short* __restrict__ clo, float* __restrict__ bnorm,
    float* __restrict__ bns,
    unsigned int* __restrict__ ctrl /* 516 u32 at ws+0 */) {
    int tid = blockIdx.x * 256 + threadIdx.x;   // 0..65535
    if (tid < 516) ctrl[tid] = 0u;
    int j = tid & 7;
    int L = (tid >> 3) & 63;
    int cs = tid >> 9;          // 0..127
    int s = cs & 1, c = cs >> 1;
    int code = c * 16 + (L & 15);
    int d = s * 32 + (L >> 4) * 8 + j;
    float v = -8192.0f * cb[(size_t)code * DIM + d];   // -2c * 4096 (exact)
    _Float16 h = (_Float16)v;                          // RN f32->f16
    float hf = (float)h;
    float lo;
    {
#pragma clang fp contract(off)
        lo = v - hf;                                   // exact in f32
    }
    _Float16 l = (_Float16)lo;
    chi[tid] = __builtin_bit_cast(unsigned short, h);
    clo[tid] = __builtin_bit_cast(unsigned short, l);

    if (tid < NCODE) {
        float bn = np_sumsq64(cb + (size_t)tid * DIM);
        bnorm[tid] = bn;
        bns[tid] = bn * 2097152.0f;                    // x 2^21 (exact)
    }
}

__device__ __forceinline__ void top2_merge(float& a1, float& a2, int& ai,
                                           float b1, float b2, int bi) {
    float n1 = fminf(a1, b1);
    float n2 = fminf(fmaxf(a1, b1), fminf(a2, b2));
    ai = (b1 < a1) ? bi : ai;   // ties keep a (exact ties get flagged anyway)
    a1 = n1; a2 = n2;
}

// ---------------------------------------------------------------------------
// Fast screen, v10 (r14): codebook-split waves. Wave cap was the bound:
// 16 tokens/wave -> 4096 waves total = 16/CU max (occupancy 24.6%, all
// pipes idle). Now block = 4 waves = 2 token-tiles x 2 codebook-halves;
// each wave scans 32 chunks (codes h*512..h*512+511) for its 16 tokens;
// grid 2048 -> 8 blocks/CU; LDS ~17KB (2-chunk dbuf groups, bnorm from
// global w/ register prefetch) -> up to 32 waves/CU. Per-code MFMA ops
// and order bitwise-identical to r13; cross-wave top-2 merge (a = lower
// half) keeps the lower index on ties = sequential-scan tie rule ->
// identical flag set / best indices. Epilogue = r2-verified 32-token
// structure (wave-0 partials bitwise-identical). LDS dbuf barrier
// cadence identical in form (1 barrier/group, now 32 groups).
// ---------------------------------------------------------------------------
__global__ __launch_bounds__(256, 8) void vq_fast(
    const float* __restrict__ z, const float* __restrict__ cb,
    const unsigned short* __restrict__ cfrag_hi,
    const unsigned short* __restrict__ cfrag_lo,
    const float* __restrict__ bnorm_s, float* __restrict__ out,
    unsigned int* __restrict__ flag_count, int* __restrict__ flag_list,
    unsigned long long* __restrict__ packed_min,
    double* __restrict__ loss_sum, unsigned int flag_cap) {
    __shared__ short8 sh_hi[2][256];   // [buf][h*128 + step*64 + lane], 8KB
    __shared__ short8 sh_lo[2][256];   // 8KB
    __shared__ float s_m1[64], s_m2[64];
    __shared__ int s_bi[64];
    __shared__ int s_best[32];
    __shared__ int s_flag[32];

    const int tid = threadIdx.x;
    const int lane = tid & 63;
    const int w = tid >> 6;                  // 0..3
    const int h = w & 1;                     // codebook half
    const int tt = w >> 1;                   // token tile
    const int t0 = blockIdx.x * 32;
    const int tw = t0 + tt * 16;             // this wave's 16 tokens
    const int col = lane & 15;
    const int quad = lane >> 4;

    // token B-fragments (fp16 hi/lo of z*512), 2 K-steps, in registers
    half8 zhi[2], zlo[2];
#pragma unroll
    for (int s = 0; s < 2; ++s) {
        const float* zp = z + (size_t)(tw + col) * DIM + s * 32 + quad * 8;
        float4 f0 = ((const float4*)zp)[0];
        float4 f1 = ((const float4*)zp)[1];
        float f[8] = {f0.x, f0.y, f0.z, f0.w, f1.x, f1.y, f1.z, f1.w};
        half8 hh8, ll8;
#pragma unroll
        for (int j = 0; j < 8; ++j) {
            float sv = f[j] * 512.0f;        // exact pow2 scale
            _Float16 hh = (_Float16)sv;      // RN
            float hf = (float)hh;
            float lo;
            {
#pragma clang fp contract(off)
                lo = sv - hf;                // exact in f32
            }
            hh8[j] = hh;
            ll8[j] = (_Float16)lo;
        }
        zhi[s] = hh8; zlo[s] = ll8;
    }

    const short8* CH = (const short8*)cfrag_hi;   // chunk c at [c*128 + e]
    const short8* CL = (const short8*)cfrag_lo;
    const f32x4* bnp = (const f32x4*)bnorm_s;     // 256 f32x4

    // staging role: thread stages element st of chunk (sc*32 + g)
    const int sc = tid >> 7;          // 0 -> half0 chunk, 1 -> half1 chunk
    const int st = tid & 127;         // element within chunk

    // stage group 0 (chunks 0 and 32)
    {
        const int c0 = sc * 32;
        sh_hi[0][tid] = CH[c0 * 128 + st];
        sh_lo[0][tid] = CL[c0 * 128 + st];
    }
    __syncthreads();

    float m1 = 3.0e38f, m2 = 3.0e38f;
    int bi = 0;
    const int koff = quad * 4;

    // bn prefetch for this wave's first chunk (h*32)
    f32x4 nbn = bnp[(h * 32) * 4 + quad];

    for (int g = 0; g < 32; ++g) {
        const int buf = g & 1;
        short8 a0, b0;
        if (g < 31) {               // issue next group's loads first
            const int cn = sc * 32 + g + 1;
            a0 = CH[cn * 128 + st];
            b0 = CL[cn * 128 + st];
        }
        const int c = h * 32 + g;    // this wave's chunk
        short8 ch0 = sh_hi[buf][h * 128 + lane];
        short8 ch1 = sh_hi[buf][h * 128 + 64 + lane];
        short8 cl0 = sh_lo[buf][h * 128 + lane];
        short8 cl1 = sh_lo[buf][h * 128 + 64 + lane];
        const f32x4 bn = nbn;
        if (g < 31) nbn = bnp[(c + 1) * 4 + quad];
        const int cbase = c * 16 + koff;
        f32x4 acc = bn;
        acc = __builtin_amdgcn_mfma_f32_16x16x32_f16(as_h8(ch0), zhi[0], acc, 0, 0, 0);
        acc = __builtin_amdgcn_mfma_f32_16x16x32_f16(as_h8(cl0), zhi[0], acc, 0, 0, 0);
        acc = __builtin_amdgcn_mfma_f32_16x16x32_f16(as_h8(ch0), zlo[0], acc, 0, 0, 0);
        acc = __builtin_amdgcn_mfma_f32_16x16x32_f16(as_h8(ch1), zhi[1], acc, 0, 0, 0);
        acc = __builtin_amdgcn_mfma_f32_16x16x32_f16(as_h8(cl1), zhi[1], acc, 0, 0, 0);
        acc = __builtin_amdgcn_mfma_f32_16x16x32_f16(as_h8(ch1), zlo[1], acc, 0, 0, 0);
#pragma unroll
        for (int i = 0; i < 4; ++i) {
            float u = acc[i];
            float om1 = m1;
            bool lt = u < om1;
            float fm = fminf(m2, u);
            m2 = lt ? om1 : fm;
            m1 = lt ? u : om1;
            bi = lt ? (cbase + i) : bi;
        }
        if (g < 31) {
            sh_hi[buf ^ 1][tid] = a0;
            sh_lo[buf ^ 1][tid] = b0;
            __syncthreads();
        }
    }

    // in-wave quad merge (lanes l, l^16, l^32, l^48 share a token column)
    {
        float a1 = m1, a2 = m2;
        int ai = bi;
        {
            float o1 = __shfl_xor(a1, 16); float o2 = __shfl_xor(a2, 16);
            int oi = __shfl_xor(ai, 16);
            top2_merge(a1, a2, ai, o1, o2, oi);
        }
        {
            float o1 = __shfl_xor(a1, 32); float o2 = __shfl_xor(a2, 32);
            int oi = __shfl_xor(ai, 32);
            top2_merge(a1, a2, ai, o1, o2, oi);
        }
        if (quad == 0) {
            const int idx = tt * 32 + h * 16 + col;
            s_m1[idx] = a1; s_m2[idx] = a2; s_bi[idx] = ai;
        }
    }
    __syncthreads();

    // cross-half merge: 32 threads, one per block token. a = half0 (lower
    // codes) so ties keep the lower index == sequential-scan tie rule.
    if (tid < 32) {
        const int jt = tid >> 4, jc = tid & 15;
        const int i0 = jt * 32 + jc;          // half 0
        const int i1 = jt * 32 + 16 + jc;     // half 1
        float a1 = s_m1[i0], a2 = s_m2[i0];
        int ai = s_bi[i0];
        top2_merge(a1, a2, ai, s_m1[i1], s_m2[i1], s_bi[i1]);
        int fl = (a2 - a1) < MARGINS;
        if (fl) {
            unsigned int pos = atomicAdd(flag_count, 1u);
            if (pos >= flag_cap) fl = 0;
            else {
                flag_list[pos] = t0 + tid;
                packed_min[pos] = ~0ull;   // lazy init (no memset node)
            }
        }
        s_best[tid] = ai;
        s_flag[tid] = fl;
    }
    __syncthreads();

    // epilogue: r2-verified 32-token structure; wave 0 only contributes,
    // same (token,h)->thread map, same 64-lane butterfly, one f64 atomic.
    const int et = tid >> 1, eh = tid & 1;
    float loss_t = 0.0f;
    if (et < 32 && !s_flag[et]) {
        const int B = s_best[et];
        const float4* cq  = (const float4*)(cb + (size_t)B * DIM + eh * 32);
        const float4* zq4 = (const float4*)(z + (size_t)(t0 + et) * DIM + eh * 32);
        float4* o4 = (float4*)(out + (size_t)(t0 + et) * DIM + eh * 32);
#pragma unroll
        for (int jj = 0; jj < 8; ++jj) {
#pragma clang fp contract(off)
            float4 cc = cq[jj];
            float4 zz = zq4[jj];
            float d0 = cc.x - zz.x, d1 = cc.y - zz.y;
            float d2 = cc.z - zz.z, d3 = cc.w - zz.w;
            float4 o;
            o.x = zz.x + d0; o.y = zz.y + d1;
            o.z = zz.z + d2; o.w = zz.w + d3;
            o4[jj] = o;
            loss_t = __fmaf_rn(d0, d0, loss_t);
            loss_t = __fmaf_rn(d1, d1, loss_t);
            loss_t = __fmaf_rn(d2, d2, loss_t);
            loss_t = __fmaf_rn(d3, d3, loss_t);
        }
        if (eh == 0) out[OUT_IDX_OFF + t0 + et] = (float)B;
    }
#pragma unroll
    for (int off = 32; off > 0; off >>= 1)
        loss_t += __shfl_down(loss_t, off);
    if (lane == 0 && w == 0) atomicAdd(loss_sum, (double)loss_t);
}

__device__ __forceinline__ unsigned long long shfl_down_u64(unsigned long long v, int off) {
    unsigned int lo = (unsigned int)v, hi = (unsigned int)(v >> 32);
    lo = __shfl_down(lo, off);
    hi = __shfl_down(hi, off);
    return ((unsigned long long)hi << 32) | lo;
}

// ---------------------------------------------------------------------------
// Exact numpy-bitwise pass, v4: UNCHANGED (verified rounds 6-10). Uses
// unscaled bnorm; arithmetic bitwise-identical.
// ---------------------------------------------------------------------------
__global__ __launch_bounds__(256) void vq_exact_min(
    const float* __restrict__ z, const float* __restrict__ cb,
    const float* __restrict__ bnorm,
    const unsigned int* __restrict__ flag_count,
    const int* __restrict__ flag_list,
    unsigned long long* __restrict__ packed_min,
    unsigned int* __restrict__ done_grp, unsigned int* __restrict__ done_all,
    float* __restrict__ out, double* __restrict__ loss_sum,
    unsigned int flag_cap) {
    __shared__ float zsh[TPG * 68];
    __shared__ float szs[TPG];
    __shared__ unsigned int s_old;

    const int tid = threadIdx.x;
    const int w = tid >> 6;
    const int lane = tid & 63;
    unsigned int count = *flag_count;
    if (count > flag_cap) count = flag_cap;
    const unsigned int ngroups = (count + TPG - 1) / TPG;   // <= 512

    if (count == 0) {   // no flagged tokens: block 0 writes the loss
        if (blockIdx.x == 0 && tid == 0) {
            double L = atomicAdd(loss_sum, 0.0);
            out[OUT_LOSS_OFF] = (float)(2.0 * L / (double)((size_t)TOKENS * DIM));
        }
        return;
    }

    const int q = blockIdx.x & 3;
    const unsigned int g = blockIdx.x >> 2;          // 0..511
    if (g >= ngroups) return;

    const int k = q * 256 + w * 64 + lane;           // this lane's code

    float row[DIM];
    {
        const float4* c4 = (const float4*)(cb + (size_t)k * DIM);
#pragma unroll
        for (int j = 0; j < 16; ++j) {
            float4 v = c4[j];
            row[4 * j + 0] = v.x; row[4 * j + 1] = v.y;
            row[4 * j + 2] = v.z; row[4 * j + 3] = v.w;
        }
    }
    const float bnk = bnorm[k];

    {
        const int i = tid >> 2, part = tid & 3;
        if (i < TPG) {
            const unsigned int li = g * TPG + i;
            if (li < count) {
                const int t = flag_list[li];
                const float4* zp = (const float4*)(z + (size_t)t * DIM + part * 16);
                float4* dst = (float4*)(zsh + i * 68 + part * 16);
#pragma unroll
                for (int e = 0; e < 4; ++e) dst[e] = zp[e];
            }
        }
    }
    __syncthreads();
    if (tid < TPG) szs[tid] = np_sumsq64(zsh + tid * 68);
    __syncthreads();

    for (int tt = 0; tt < TPG; ++tt) {
        const unsigned int li = g * TPG + tt;
        const float* zp = zsh + tt * 68;             // wave-uniform -> broadcast
        float l16[16];
#pragma unroll
        for (int g2 = 0; g2 < 4; ++g2) {
            float4 v0 = ((const float4*)(zp + 4 * g2))[0];
            float4 v1 = ((const float4*)(zp + 16 + 4 * g2))[0];
            float4 v2 = ((const float4*)(zp + 32 + 4 * g2))[0];
            float4 v3 = ((const float4*)(zp + 48 + 4 * g2))[0];
            float a0[4] = {v0.x, v0.y, v0.z, v0.w};
            float a1[4] = {v1.x, v1.y, v1.z, v1.w};
            float a2[4] = {v2.x, v2.y, v2.z, v2.w};
            float a3[4] = {v3.x, v3.y, v3.z, v3.w};
#pragma unroll
            for (int e = 0; e < 4; ++e) {
#pragma clang fp contract(off)
                int jj = 4 * g2 + e;
                float acc = a3[e] * row[48 + jj];
                acc = __fmaf_rn(a2[e], row[32 + jj], acc);
                acc = __fmaf_rn(a1[e], row[16 + jj], acc);
                acc = __fmaf_rn(a0[e], row[jj],      acc);
                l16[jj] = acc;
            }
        }
        float e_np;
        {
#pragma clang fp contract(off)
#pragma unroll
            for (int jj = 0; jj < 8; ++jj) l16[jj] = l16[jj] + l16[jj + 8];
#pragma unroll
            for (int jj = 0; jj < 4; ++jj) l16[jj] = l16[jj] + l16[jj + 4];
            l16[0] = l16[0] + l16[2];
            l16[1] = l16[1] + l16[3];
            e_np = l16[0] + l16[1];
        }
        float dd;
        {
#pragma clang fp contract(off)
            float t1 = szs[tt] + bnk;
            float mm = 2.0f * e_np;
            dd = t1 - mm;
        }
        unsigned long long pk =
            ((unsigned long long)__float_as_uint(dd) << 10) | (unsigned int)k;
#pragma unroll
        for (int off = 32; off > 0; off >>= 1) {
            unsigned long long o = shfl_down_u64(pk, off);
            pk = (o < pk) ? o : pk;
        }
        if (lane == 0 && li < count)
            atomicMin(&packed_min[li], pk);
    }

    // ---- fused finish: 4th quarter-block of this group writes outputs ----
    __threadfence();
    __syncthreads();
    if (tid == 0) s_old = atomicAdd(&done_grp[g], 1u);
    __syncthreads();
    if (s_old != 3u) return;
    __threadfence();

    for (int tt = w * (TPG / 4); tt < (w + 1) * (TPG / 4); ++tt) {
        const unsigned int li = g * TPG + tt;
        if (li >= count) break;
        const int t = flag_list[li];
        const unsigned long long pk = atomicAdd(&packed_min[li], 0ull);  // coherent
        const int best = (int)(pk & 1023ull);
        const float zl = zsh[tt * 68 + lane];
        const float zq = cb[(size_t)best * DIM + lane];
        float d, o;
        {
#pragma clang fp contract(off)
            d = zq - zl;
            o = zl + d;
        }
        out[(size_t)t * DIM + lane] = o;
        float l2 = d * d;
#pragma unroll
        for (int off = 32; off > 0; off >>= 1)
            l2 += __shfl_down(l2, off);
        if (lane == 0) {
            out[OUT_IDX_OFF + t] = (float)best;
            atomicAdd(loss_sum, (double)l2);
        }
    }

    __threadfence();
    __syncthreads();
    if (tid == 0) {
        unsigned int old = atomicAdd(done_all, 1u);
        if (old == ngroups - 1) {
            double L = atomicAdd(loss_sum, 0.0);   // coherent read-through
            out[OUT_LOSS_OFF] = (float)(2.0 * L / (double)((size_t)TOKENS * DIM));
        }
    }
}

extern "C" void kernel_launch(void* const* d_in, const int* in_sizes, int n_in,
                              void* d_out, int out_size, void* d_ws, size_t ws_size,
                              hipStream_t stream) {
    const float* z  = (const float*)d_in[0];   // [8,8192,64] f32
    const float* cb = (const float*)d_in[1];   // [1024,64] f32
    float* out = (float*)d_out;

    char* ws = (char*)d_ws;
    double* loss_sum = (double*)(ws + WS_LOSS);
    unsigned int* flag_count = (unsigned int*)(ws + WS_FLAGC);
    unsigned int* done_all = (unsigned int*)(ws + WS_DONEA);
    unsigned int* done_grp = (unsigned int*)(ws + WS_DGRP);
    float* bnorm = (float*)(ws + WS_BNORM);
    float* bns = (float*)(ws + WS_BNS);
    unsigned short* chi = (unsigned short*)(ws + WS_CHI);
    unsigned short* clo = (unsigned short*)(ws + WS_CLO);
    unsigned long long* packed = (unsigned long long*)(ws + WS_PACKED);
    int* flag_list = (int*)(ws + WS_FLAGS);

    unsigned int cap = 0;
    if (ws_size > WS_FLAGS + 4) {
        size_t c = (ws_size - WS_FLAGS) / 4;
        cap = (c > FLAG_CAP) ? FLAG_CAP : (unsigned int)c;
    }

    vq_prep<<<dim3(256), dim3(256), 0, stream>>>(
        cb, chi, clo, bnorm, bns, (unsigned int*)ws);
    vq_fast<<<dim3(TOKENS / 32), dim3(256), 0, stream>>>(
        z, cb, chi, clo, bns, out, flag_count, flag_list, packed, loss_sum, cap);
    vq_exact_min<<<dim3(2048), dim3(256), 0, stream>>>(
        z, cb, bnorm, flag_count, flag_list, packed, done_grp, done_all,
        out, loss_sum, cap);
}